// Round 7
// baseline (3002.482 us; speedup 1.0000x reference)
//
#include <hip/hip_runtime.h>
#include <math.h>

#define NS   512   // states
#define NO   1024  // observations
#define NB   64    // batch
#define TMAX 512

// A as fp8: 32 chunks of 16 values per state-row.
#define QL 18      // chunks in LDS (144 KB)      : k 0..287
#define QS 14      // chunks streamed from L2     : k 288..511

typedef _Float16 h2v __attribute__((ext_vector_type(2)));
typedef float    f2v __attribute__((ext_vector_type(2)));

#if defined(__has_builtin)
#if __has_builtin(__builtin_amdgcn_cvt_pk_f16_fp8)
#define HAVE_F16CVT 1
#endif
#endif

__device__ inline float wave_red_sum(float x) {
#pragma unroll
  for (int o = 32; o; o >>= 1) x += __shfl_xor(x, o, 64);
  return x;
}
__device__ inline float wave_red_max(float x) {
#pragma unroll
  for (int o = 32; o; o >>= 1) x = fmaxf(x, __shfl_xor(x, o, 64));
  return x;
}

#ifdef HAVE_F16CVT
__device__ inline float dot2h(h2v a, unsigned vb, float c) {
#if __has_builtin(__builtin_amdgcn_fdot2)
  return __builtin_amdgcn_fdot2(a, __builtin_bit_cast(h2v, vb), c, false);
#else
  h2v bv = __builtin_bit_cast(h2v, vb);
  return c + (float)a.x * (float)bv.x + (float)a.y * (float)bv.y;
#endif
}
// one fp8x16 chunk dotted against 16 fp16 v values (two uint4)
__device__ inline void cdot(uint4 a, uint4 v0, uint4 v1, float& acc) {
  acc = dot2h(__builtin_amdgcn_cvt_pk_f16_fp8((short)(a.x)), v0.x, acc);
  acc = dot2h(__builtin_amdgcn_cvt_pk_f16_fp8((short)(a.x >> 16)), v0.y, acc);
  acc = dot2h(__builtin_amdgcn_cvt_pk_f16_fp8((short)(a.y)), v0.z, acc);
  acc = dot2h(__builtin_amdgcn_cvt_pk_f16_fp8((short)(a.y >> 16)), v0.w, acc);
  acc = dot2h(__builtin_amdgcn_cvt_pk_f16_fp8((short)(a.z)), v1.x, acc);
  acc = dot2h(__builtin_amdgcn_cvt_pk_f16_fp8((short)(a.z >> 16)), v1.y, acc);
  acc = dot2h(__builtin_amdgcn_cvt_pk_f16_fp8((short)(a.w)), v1.z, acc);
  acc = dot2h(__builtin_amdgcn_cvt_pk_f16_fp8((short)(a.w >> 16)), v1.w, acc);
}
#else
// fallback: fp8 -> f32 pairs (gfx940+), fmaf against f32 v (four float4)
__device__ inline void cdot(uint4 a, const float4* vf, float& acc) {
  f2v lo, hi;
  lo = __builtin_amdgcn_cvt_pk_f32_fp8((int)a.x, false);
  hi = __builtin_amdgcn_cvt_pk_f32_fp8((int)a.x, true);
  acc = fmaf(lo.x, vf[0].x, acc); acc = fmaf(lo.y, vf[0].y, acc);
  acc = fmaf(hi.x, vf[0].z, acc); acc = fmaf(hi.y, vf[0].w, acc);
  lo = __builtin_amdgcn_cvt_pk_f32_fp8((int)a.y, false);
  hi = __builtin_amdgcn_cvt_pk_f32_fp8((int)a.y, true);
  acc = fmaf(lo.x, vf[1].x, acc); acc = fmaf(lo.y, vf[1].y, acc);
  acc = fmaf(hi.x, vf[1].z, acc); acc = fmaf(hi.y, vf[1].w, acc);
  lo = __builtin_amdgcn_cvt_pk_f32_fp8((int)a.z, false);
  hi = __builtin_amdgcn_cvt_pk_f32_fp8((int)a.z, true);
  acc = fmaf(lo.x, vf[2].x, acc); acc = fmaf(lo.y, vf[2].y, acc);
  acc = fmaf(hi.x, vf[2].z, acc); acc = fmaf(hi.y, vf[2].w, acc);
  lo = __builtin_amdgcn_cvt_pk_f32_fp8((int)a.w, false);
  hi = __builtin_amdgcn_cvt_pk_f32_fp8((int)a.w, true);
  acc = fmaf(lo.x, vf[3].x, acc); acc = fmaf(lo.y, vf[3].y, acc);
  acc = fmaf(hi.x, vf[3].z, acc); acc = fmaf(hi.y, vf[3].w, acc);
}
#endif

// P1: pi softmax -> pi_sm[512]
__global__ void k_pi(const float* __restrict__ pi, float* __restrict__ pi_sm) {
  __shared__ float red[8];
  int tid = threadIdx.x;
  float v = pi[tid];
  float m = wave_red_max(v);
  if ((tid & 63) == 0) red[tid >> 6] = m;
  __syncthreads();
  m = fmaxf(fmaxf(fmaxf(red[0], red[1]), fmaxf(red[2], red[3])),
            fmaxf(fmaxf(red[4], red[5]), fmaxf(red[6], red[7])));
  float e = __expf(v - m);
  float s = wave_red_sum(e);
  __syncthreads();
  if ((tid & 63) == 0) red[tid >> 6] = s;
  __syncthreads();
  s = red[0] + red[1] + red[2] + red[3] + red[4] + red[5] + red[6] + red[7];
  pi_sm[tid] = e / s;
}

// P2: per-column (axis 0) logsumexp of A + pow2 fp8 scale factors.
__global__ void k_colLse(const float* __restrict__ A, float* __restrict__ lseA,
                         float* __restrict__ scaleA, float* __restrict__ sinvA) {
  __shared__ float redm[4];
  __shared__ float reds[4];
  int k = blockIdx.x, tid = threadIdx.x;
  float a0 = A[tid * NS + k], a1 = A[(tid + 256) * NS + k];
  float m = wave_red_max(fmaxf(a0, a1));
  if ((tid & 63) == 0) redm[tid >> 6] = m;
  __syncthreads();
  m = fmaxf(fmaxf(redm[0], redm[1]), fmaxf(redm[2], redm[3]));
  float s = __expf(a0 - m) + __expf(a1 - m);
  s = wave_red_sum(s);
  if ((tid & 63) == 0) reds[tid >> 6] = s;
  __syncthreads();
  s = reds[0] + reds[1] + reds[2] + reds[3];
  if (tid == 0) {
    float lse = m + __logf(s);
    lseA[k] = lse;
    // colmax of softmax = exp(m - lse); scale = min(2^9, 2^floor(log2(448/max)))
    float e = floorf(8.8073549f + (lse - m) * 1.44269504f);
    if (e > 9.f) e = 9.f;
    scaleA[k] = exp2f(e);
    sinvA[k]  = exp2f(-e);
  }
}

// P3: row logsumexp of E (axis 1). One block per row. grid 512 x 256.
__global__ void k_rowLseE(const float* __restrict__ E, float* __restrict__ lseE) {
  __shared__ float red[4];
  int i = blockIdx.x, tid = threadIdx.x;
  const float* row = E + i * NO;
  float a0 = row[tid], a1 = row[tid + 256], a2 = row[tid + 512], a3 = row[tid + 768];
  float m = fmaxf(fmaxf(a0, a1), fmaxf(a2, a3));
  m = wave_red_max(m);
  if ((tid & 63) == 0) red[tid >> 6] = m;
  __syncthreads();
  m = fmaxf(fmaxf(red[0], red[1]), fmaxf(red[2], red[3]));
  float s = __expf(a0 - m) + __expf(a1 - m) + __expf(a2 - m) + __expf(a3 - m);
  s = wave_red_sum(s);
  __syncthreads();
  if ((tid & 63) == 0) red[tid >> 6] = s;
  __syncthreads();
  s = red[0] + red[1] + red[2] + red[3];
  if (tid == 0) lseE[i] = m + __logf(s);
}

// P4: pack a'_ik = exp(A-lseA[k])*scaleA[k] as fp8 e4m3, chunk-major:
// uint4 chunk c (k=16c..16c+15) for state i lives at Apk4[c*512+i].
// Word granularity: u -> c=u>>11, i=(u&2047)>>2, w=u&3, k0=16c+4w.
__global__ void k_pack(const float* __restrict__ A, const float* __restrict__ lseA,
                       const float* __restrict__ scaleA, unsigned* __restrict__ W) {
  int u = blockIdx.x * 512 + threadIdx.x;   // [0, 65536)
  int w = u & 3, i = (u >> 2) & 511, c = u >> 11;
  int k0 = c * 16 + w * 4;
  const float* Ar = A + i * NS + k0;
  float a0 = __expf(Ar[0] - lseA[k0 + 0]) * scaleA[k0 + 0];
  float a1 = __expf(Ar[1] - lseA[k0 + 1]) * scaleA[k0 + 1];
  float a2 = __expf(Ar[2] - lseA[k0 + 2]) * scaleA[k0 + 2];
  float a3 = __expf(Ar[3] - lseA[k0 + 3]) * scaleA[k0 + 3];
  int lo = __builtin_amdgcn_cvt_pk_fp8_f32(a0, a1, 0, false);
  int v  = __builtin_amdgcn_cvt_pk_fp8_f32(a2, a3, lo, true);
  W[u] = (unsigned)v;
}

// P5: transposed exp'd emissions: Et[o][i] = fp16(exp(E[i][o] - lseE[i])).
__global__ void k_Et(const float* __restrict__ E, const float* __restrict__ lseE,
                     _Float16* __restrict__ Et) {
  int o = blockIdx.x, i = threadIdx.x;
  Et[o * NS + i] = (_Float16)__expf(E[i * NO + o] - lseE[i]);
}

// Main forward: one block of 512 threads per batch, thread = state i.
// A fp8: 18 chunks in LDS + 14 streamed from L2 per step. v unnormalized
// (scale applied next step via rcp(s_prev)); ONE barrier per step.
__global__ __launch_bounds__(512) void k_fwd(
    const _Float16* __restrict__ Et, const int* __restrict__ x,
    const int* __restrict__ Tlen, const float* __restrict__ pi_sm,
    const float* __restrict__ sinvA, const uint4* __restrict__ Apk4,
    float* __restrict__ out) {
  __shared__ uint4 Alds[QL * 512];     // 147456 B
#ifdef HAVE_F16CVT
  __shared__ uint4 vbuf[2][NS / 8];    // fp16 v, 1 KB each
#else
  __shared__ float4 vbuf[2][NS / 4];   // f32 v, 2 KB each
#endif
  __shared__ int xrow[TMAX];           // 2 KB
  __shared__ float red[2][8];
  int b = blockIdx.x, tid = threadIdx.x;

#pragma unroll
  for (int q = 0; q < QL; q++) Alds[q * 512 + tid] = Apk4[q * 512 + tid];
  const uint4* Astr = Apk4 + QL * 512 + tid;

  xrow[tid] = x[b * TMAX + tid];

  float pi_i = pi_sm[tid];
  float cinv = sinvA[tid];             // pow2, folds fp8 column scale into v
  const _Float16* Etc = Et + tid;
  int Tb = Tlen[b];
  float cacc = 0.f;
  int cur = 0;
  __syncthreads();

  for (int t = 0; t < Tb; t++) {
    int xt = xrow[t];
    _Float16 emh = Etc[(size_t)xt * NS];   // coalesced, hidden by dot phase
    float acc_s;
    if (t == 0) {
      acc_s = pi_i;
    } else {
      float sp = ((red[cur][0] + red[cur][1]) + (red[cur][2] + red[cur][3])) +
                 ((red[cur][4] + red[cur][5]) + (red[cur][6] + red[cur][7]));
      cacc += __logf(sp);
      float rs = __builtin_amdgcn_rcpf(sp);
      // issue streamed chunks first; consumed last (L2 latency hidden)
      uint4 sb[QS];
#pragma unroll
      for (int q = 0; q < QS; q++) sb[q] = Astr[q * 512];
      float ac[4] = {0.f, 0.f, 0.f, 0.f};
#ifdef HAVE_F16CVT
      const uint4* vb4 = vbuf[cur];
#pragma unroll
      for (int c = 0; c < QL; c++)
        cdot(Alds[c * 512 + tid], vb4[2 * c], vb4[2 * c + 1], ac[c & 3]);
#pragma unroll
      for (int q = 0; q < QS; q++)
        cdot(sb[q], vb4[2 * (QL + q)], vb4[2 * (QL + q) + 1], ac[q & 3]);
#else
      const float4* vbf = vbuf[cur];
#pragma unroll
      for (int c = 0; c < QL; c++)
        cdot(Alds[c * 512 + tid], vbf + 4 * c, ac[c & 3]);
#pragma unroll
      for (int q = 0; q < QS; q++)
        cdot(sb[q], vbf + 4 * (QL + q), ac[q & 3]);
#endif
      acc_s = ((ac[0] + ac[1]) + (ac[2] + ac[3])) * rs;
    }
    float nv = acc_s * (float)emh;
    float wsum = wave_red_sum(nv);
    int nxt = cur ^ 1;
    if ((tid & 63) == 0) red[nxt][tid >> 6] = wsum;
#ifdef HAVE_F16CVT
    ((_Float16*)vbuf[nxt])[tid] = (_Float16)(nv * cinv);
#else
    ((float*)vbuf[nxt])[tid] = nv * cinv;
#endif
    __syncthreads();
    cur = nxt;
  }
  if (tid == 0) {
    float sp = ((red[cur][0] + red[cur][1]) + (red[cur][2] + red[cur][3])) +
               ((red[cur][4] + red[cur][5]) + (red[cur][6] + red[cur][7]));
    out[b] = cacc + __logf(sp);
  }
}

extern "C" void kernel_launch(void* const* d_in, const int* in_sizes, int n_in,
                              void* d_out, int out_size, void* d_ws, size_t ws_size,
                              hipStream_t stream) {
  const float* pi = (const float*)d_in[0];
  const float* A  = (const float*)d_in[1];
  const float* E  = (const float*)d_in[2];
  const int*   x  = (const int*)d_in[3];
  const int*   T  = (const int*)d_in[4];
  float* out = (float*)d_out;

  char* ws = (char*)d_ws;
  float*    pi_sm  = (float*)(ws + 0);
  float*    lseA   = (float*)(ws + 2048);
  float*    lseE   = (float*)(ws + 4096);
  float*    sinvA  = (float*)(ws + 6144);
  float*    scaleA = (float*)(ws + 8192);
  unsigned* Apk    = (unsigned*)(ws + 10240);              // 256 KB fp8
  _Float16* Et     = (_Float16*)(ws + 10240 + 262144);     // 1 MB

  hipLaunchKernelGGL(k_pi,      dim3(1),    dim3(512), 0, stream, pi, pi_sm);
  hipLaunchKernelGGL(k_colLse,  dim3(512),  dim3(256), 0, stream, A, lseA, scaleA, sinvA);
  hipLaunchKernelGGL(k_rowLseE, dim3(512),  dim3(256), 0, stream, E, lseE);
  hipLaunchKernelGGL(k_pack,    dim3(128),  dim3(512), 0, stream, A, lseA, scaleA, Apk);
  hipLaunchKernelGGL(k_Et,      dim3(1024), dim3(512), 0, stream, E, lseE, Et);
  hipLaunchKernelGGL(k_fwd,     dim3(64),   dim3(512), 0, stream,
                     Et, x, T, pi_sm, sinvA, (const uint4*)Apk, out);
}